// Round 7
// baseline (111.967 us; speedup 1.0000x reference)
//
#include <hip/hip_runtime.h>

// RegistrationRecall: out = (sqrt(mean_n(min_m ||src_n - tgt_m||)^2) < 0.1) ? 1 : 0
// N = M = 8192, D = 3, fp32.
//
// R7 = DIAGNOSTIC round. Structure is the best-measured variant (R2, 68.0 us
// total): wave owns S=4 sources, lanes split targets, 3 float4 global loads
// per 4 targets per lane. knn_partial is launched 4x (idempotent: each launch
// writes identical partials). Marginal cost of the 3 extra launches measures
// the kernel's true in-graph duration, which rocprof can't show (top-5 slots
// are all taken by the harness's 39.5us d_ws poison fills):
//   total ~= 68 + 3*t_knn  ->  t_knn = (total - 68)/3.

#define N_SRC 8192
#define N_TGT 8192
#define S     4                         // sources per wave
#define BLOCK 256                       // 4 waves per block
#define GROUPS (N_SRC / S)              // 2048 wave-groups
#define NBLOCKS (GROUPS / 4)            // 512 blocks
#define TGT_PER_LANE_ITER 4
#define ITERS (N_TGT / (64 * TGT_PER_LANE_ITER))   // 32

__global__ __launch_bounds__(BLOCK) void knn_partial(const float* __restrict__ src,
                                                     const float* __restrict__ tgt,
                                                     float* __restrict__ partials) {
    const int tid  = threadIdx.x;
    const int lane = tid & 63;
    const int wave = tid >> 6;
    const int g    = blockIdx.x * 4 + wave;        // source group id

    float sx[S], sy[S], sz[S];
    const float* sp = src + g * S * 3;
    #pragma unroll
    for (int i = 0; i < S; ++i) {
        sx[i] = sp[3 * i + 0];
        sy[i] = sp[3 * i + 1];
        sz[i] = sp[3 * i + 2];
    }

    float m[S];
    #pragma unroll
    for (int i = 0; i < S; ++i) m[i] = 1e30f;

    const float* tb = tgt + lane * (TGT_PER_LANE_ITER * 3);

    #pragma unroll 2
    for (int it = 0; it < ITERS; ++it) {
        const float4 t0 = *(const float4*)(tb + 0);
        const float4 t1 = *(const float4*)(tb + 4);
        const float4 t2 = *(const float4*)(tb + 8);
        tb += 64 * TGT_PER_LANE_ITER * 3;

        const float tx[4] = {t0.x, t0.w, t1.z, t2.y};
        const float ty[4] = {t0.y, t1.x, t1.w, t2.z};
        const float tz[4] = {t0.z, t1.y, t2.x, t2.w};

        #pragma unroll
        for (int j = 0; j < 4; ++j) {
            #pragma unroll
            for (int i = 0; i < S; ++i) {
                const float dx = sx[i] - tx[j];
                const float dy = sy[i] - ty[j];
                const float dz = sz[i] - tz[j];
                const float d2 = dx * dx + dy * dy + dz * dz;
                m[i] = fminf(m[i], d2);
            }
        }
    }

    // butterfly min across the 64 lanes for each of the 4 sources
    #pragma unroll
    for (int off = 1; off < 64; off <<= 1) {
        #pragma unroll
        for (int i = 0; i < S; ++i)
            m[i] = fminf(m[i], __shfl_xor(m[i], off));
    }

    // replicate reference rounding: d = sqrt(min d2); accumulate d*d
    float c = 0.0f;
    #pragma unroll
    for (int i = 0; i < S; ++i) {
        const float d = sqrtf(m[i]);
        c += d * d;
    }

    __shared__ float wsum[BLOCK / 64];
    if (lane == 0) wsum[wave] = c;
    __syncthreads();
    if (tid == 0)
        partials[blockIdx.x] = wsum[0] + wsum[1] + wsum[2] + wsum[3];
}

__global__ __launch_bounds__(256) void knn_finalize(const float* __restrict__ partials,
                                                    float* __restrict__ out) {
    const int tid = threadIdx.x;
    float v = partials[tid] + partials[tid + 256];   // NBLOCKS = 512 partials

    #pragma unroll
    for (int off = 1; off < 64; off <<= 1)
        v += __shfl_xor(v, off);

    __shared__ float wsum[4];
    if ((tid & 63) == 0) wsum[tid >> 6] = v;
    __syncthreads();
    if (tid == 0) {
        const float total = wsum[0] + wsum[1] + wsum[2] + wsum[3];
        const float rmse = sqrtf(total / (float)N_SRC);
        out[0] = (rmse < 0.1f) ? 1.0f : 0.0f;
    }
}

extern "C" void kernel_launch(void* const* d_in, const int* in_sizes, int n_in,
                              void* d_out, int out_size, void* d_ws, size_t ws_size,
                              hipStream_t stream) {
    const float* src = (const float*)d_in[0];
    const float* tgt = (const float*)d_in[1];
    float* partials  = (float*)d_ws;     // NBLOCKS floats
    float* out       = (float*)d_out;

    // 4 identical launches: marginal cost of launches 2-4 = 3 * t_knn.
    knn_partial<<<NBLOCKS, BLOCK, 0, stream>>>(src, tgt, partials);
    knn_partial<<<NBLOCKS, BLOCK, 0, stream>>>(src, tgt, partials);
    knn_partial<<<NBLOCKS, BLOCK, 0, stream>>>(src, tgt, partials);
    knn_partial<<<NBLOCKS, BLOCK, 0, stream>>>(src, tgt, partials);
    knn_finalize<<<1, 256, 0, stream>>>(partials, out);
}